// Round 4
// baseline (7238.386 us; speedup 1.0000x reference)
//
#include <hip/hip_runtime.h>
#include <hip/hip_bf16.h>

// ---------------------------------------------------------------------------
// 2-layer LSTM, B=64 T=256 N=512 H=1024.
// R4: time-multiplexed pods. Rows 0-31 (pod A) and 32-63 (pod B) are
// independent recurrences; all 256 WGs alternate A(e), B(e) phases so the
// publish->poll->consume latency of one pod hides under the other pod's
// compute. Per phase: 128-unit x 2-rowgroup split (M=16). Weights stay in
// VGPRs; dataflow flags (per-pod 256 words); acquire-inv before staging.
// ---------------------------------------------------------------------------

#define T_ 256
#define B_ 64
#define N_ 512
#define H_ 1024
#define FH_ 4096
#define NWG_SEQ 256
#define BH_ (B_ * H_)

typedef _Float16 f16;
typedef _Float16 f16x4 __attribute__((ext_vector_type(4)));
typedef _Float16 f16x8 __attribute__((ext_vector_type(8)));
typedef float f32x4 __attribute__((ext_vector_type(4)));

template <bool V> struct BC { static constexpr bool value = V; };

__device__ __forceinline__ float sigf(float x) { return 1.f / (1.f + __expf(-x)); }
__device__ __forceinline__ float tanhf_fast(float x) { return 1.f - 2.f / (__expf(2.f * x) + 1.f); }

// uncached (agent-scope, MALL-coherent) accessors
__device__ __forceinline__ void st_u64g(unsigned long long* p, unsigned long long v) {
  __hip_atomic_store(p, v, __ATOMIC_RELAXED, __HIP_MEMORY_SCOPE_AGENT);
}
__device__ __forceinline__ unsigned long long ld_u64g(const unsigned long long* p) {
  return __hip_atomic_load(p, __ATOMIC_RELAXED, __HIP_MEMORY_SCOPE_AGENT);
}
__device__ __forceinline__ void st_u32g(unsigned* p, unsigned v) {
  __hip_atomic_store(p, v, __ATOMIC_RELAXED, __HIP_MEMORY_SCOPE_AGENT);
}
__device__ __forceinline__ void st_f32g(float* p, float v) {
  union { float f; unsigned u; } c; c.f = v;
  st_u32g((unsigned*)p, c.u);
}

// ---------------------------------------------------------------------------
// init / convert kernel
// ---------------------------------------------------------------------------
__global__ __launch_bounds__(256) void init_all(
    const float* __restrict__ x, const float* __restrict__ h,
    const float* __restrict__ Wih0, const float* __restrict__ bih0, const float* __restrict__ bhh0,
    const float* __restrict__ Whh0, const float* __restrict__ Wih1, const float* __restrict__ Whh1,
    const float* __restrict__ bih1, const float* __restrict__ bhh1,
    f16* __restrict__ xT, f16* __restrict__ wih0, f16* __restrict__ whh0,
    f16* __restrict__ wih1, f16* __restrict__ whh1,
    float* __restrict__ bias0, float* __restrict__ bias1,
    f16* __restrict__ hinit, unsigned* __restrict__ flags)
{
  const int stride = gridDim.x * blockDim.x;
  const int t0 = blockIdx.x * blockDim.x + threadIdx.x;

  for (int i = t0; i < T_ * B_ * N_; i += stride) {
    int n = i & (N_ - 1);
    int tb = i >> 9;
    int b = tb & (B_ - 1);
    int t = tb >> 6;
    xT[i] = (f16)x[((size_t)b * T_ + t) * N_ + n];
  }
  for (int i = t0; i < FH_ * N_; i += stride) wih0[i] = (f16)Wih0[i];
  for (int i = t0; i < FH_ * H_; i += stride) {
    whh0[i] = (f16)Whh0[i];
    wih1[i] = (f16)Wih1[i];
    whh1[i] = (f16)Whh1[i];
  }
  for (int i = t0; i < FH_; i += stride) {
    bias0[i] = bih0[i] + bhh0[i];
    bias1[i] = bih1[i] + bhh1[i];
  }
  for (int i = t0; i < 2 * BH_; i += stride) hinit[i] = (f16)h[i];
  if (t0 < 512) flags[t0] = 0u;
}

// ---------------------------------------------------------------------------
// GEMM: pre0T[t][col][b] = (xT @ wih0^T + bias0), stored f16 TRANSPOSED.
// ---------------------------------------------------------------------------
__global__ __launch_bounds__(256) void gemm_pre0(
    const f16* __restrict__ xT, const f16* __restrict__ wih0,
    const float* __restrict__ bias0, f16* __restrict__ pre0T)
{
  const int wid = threadIdx.x >> 6;
  const int lane = threadIdx.x & 63;
  const int lr = lane & 15;
  const int lkq = (lane >> 4) << 3;
  const int lrq = (lane >> 4) << 2;

  const int mt = blockIdx.x & 255;
  const int ct = (blockIdx.x >> 8) * 4 + wid;
  const int row0 = mt * 64, col0 = ct * 64;

  f32x4 acc[4][4] = {};
  const f16* Abase = xT + (size_t)row0 * N_;

  #pragma unroll 2
  for (int kk = 0; kk < N_ / 32; ++kk) {
    const int k = kk * 32 + lkq;
    f16x8 a[4], b[4];
    #pragma unroll
    for (int r = 0; r < 4; ++r)
      a[r] = *(const f16x8*)(Abase + (size_t)(r * 16 + lr) * N_ + k);
    #pragma unroll
    for (int cf = 0; cf < 4; ++cf)
      b[cf] = *(const f16x8*)(wih0 + (size_t)(col0 + cf * 16 + lr) * N_ + k);
    #pragma unroll
    for (int r = 0; r < 4; ++r)
      #pragma unroll
      for (int cf = 0; cf < 4; ++cf)
        acc[r][cf] = __builtin_amdgcn_mfma_f32_16x16x32_f16(a[r], b[cf], acc[r][cf], 0, 0, 0);
  }

  #pragma unroll
  for (int r = 0; r < 4; ++r) {
    #pragma unroll
    for (int cf = 0; cf < 4; ++cf) {
      const int col = col0 + cf * 16 + lr;
      const float bv = bias0[col];
      f16x4 pv;
      #pragma unroll
      for (int ri = 0; ri < 4; ++ri) pv[ri] = (f16)(acc[r][cf][ri] + bv);
      *(f16x4*)(pre0T + ((size_t)mt * FH_ + col) * 64 + r * 16 + lrq) = pv;
    }
  }
}

// ---------------------------------------------------------------------------
// Persistent time-multiplexed kernel. 256 WGs x 256 threads (1 WG/CU).
// Phase (P, e): all 256 WGs work on pod P (batch rows P*32..P*32+31).
//   WG -> rgrp = wg>>7 (16 rows), ub = (wg&127)*8 (8 units per gate).
//   layer0 computes step e, layer1 computes step e-1 (same pod).
// Flags: flags[P*256 + wg] = number of completed (P,*) phases.
// ---------------------------------------------------------------------------
__global__ __launch_bounds__(256) void lstm_seq(
    const f16* __restrict__ pre0T, const f16* __restrict__ whh0,
    const f16* __restrict__ wih1, const f16* __restrict__ whh1,
    const float* __restrict__ bias1, const f16* __restrict__ hinit,
    const float* __restrict__ cin,
    f16* __restrict__ h0buf, f16* __restrict__ h1buf,
    float* __restrict__ out, unsigned* __restrict__ flags)
{
  __shared__ __align__(16) unsigned char ldsA[32768];   // h0 tile (16 rows, swizzled)
  __shared__ __align__(16) union SMB {
    unsigned char b[32768];                             // h1 tile (swizzled)
    float exc[2][4][16][33];                            // partial-sum exchange
  } smB;
  __shared__ __align__(16) f16 smH[2][16][8];           // packed h outputs

  const int tid = threadIdx.x;
  const int p = tid >> 6;          // wave = K-quarter
  const int lane = tid & 63;
  const int lr = lane & 15;
  const int lq = lane >> 4;
  const int lkq = lq << 3;
  const int lrq = lq << 2;

  const int wg = blockIdx.x;
  const int rgrp = wg >> 7;        // row-group within pod (16 rows)
  const int ub = (wg & 127) << 3;  // unit base: 8 units per gate

  // ---- preload weight fragments into registers (48 x f16x8) ----
  f16x8 l0w[2][8], l1aw[2][8], l1bw[2][8];
  #pragma unroll
  for (int cf = 0; cf < 2; ++cf) {
    const size_t wr = (size_t)((2 * cf + (lr >> 3)) * H_ + ub + (lr & 7)) * H_;
    #pragma unroll
    for (int j = 0; j < 8; ++j) {
      const int k = (p * 8 + j) * 32 + lkq;
      l0w[cf][j]  = *(const f16x8*)(whh0 + wr + k);
      l1aw[cf][j] = *(const f16x8*)(wih1 + wr + k);
      l1bw[cf][j] = *(const f16x8*)(whh1 + wr + k);
    }
  }

  // ---- per-thread cell state: thread owns one (pod, row, unit) cell ----
  const int tp = tid >> 7;         // this thread's pod for updates
  const int crow = tid & 15;
  const int cu = (tid >> 4) & 7;
  const int prow = tp * 32 + rgrp * 16 + crow;
  const size_t cell = (size_t)prow * H_ + ub + cu;
  float c0 = cin[cell];
  float c1 = cin[(size_t)BH_ + cell];
  float b1v[4];
  #pragma unroll
  for (int g = 0; g < 4; ++g) b1v[g] = bias1[g * H_ + ub + cu];

  float* outh = out + (size_t)B_ * T_ * H_;
  float* outc = outh + 2 * BH_;

  auto phase = [&](auto A0c, auto A1c, int P, int e) {
    constexpr bool A0 = decltype(A0c)::value;
    constexpr bool A1 = decltype(A1c)::value;
    const int pr0 = P * 32 + rgrp * 16;

    // pre0T prefetch (no flag dependence) BEFORE the poll
    float pf[4];
    if (A0 && tp == P) {
      #pragma unroll
      for (int g = 0; g < 4; ++g)
        pf[g] = (float)pre0T[((size_t)e * FH_ + g * H_ + ub + cu) * 64 + prow];
    }

    // poll: all 256 pod-P flags >= e (wave 0)
    if (e > 0 && p == 0) {
      const unsigned long long* fp = (const unsigned long long*)(flags + P * 256);
      for (;;) {
        unsigned long long v0 = ld_u64g(&fp[lane]);
        unsigned long long v1 = ld_u64g(&fp[64 + lane]);
        const bool ok = ((unsigned)v0 >= (unsigned)e) && ((unsigned)(v0 >> 32) >= (unsigned)e)
                     && ((unsigned)v1 >= (unsigned)e) && ((unsigned)(v1 >> 32) >= (unsigned)e);
        if (__ballot(ok) == ~0ull) break;
        __builtin_amdgcn_s_sleep(1);
      }
    }
    __syncthreads();
    if (e > 0) __builtin_amdgcn_fence(__ATOMIC_ACQUIRE, "agent");  // inv stale lines

    // stage h0_P[e-1] (16 rows x 1024, 32KB) -- used by layer0 AND layer1
    {
      const f16* h0src = (e == 0) ? hinit : h0buf + (size_t)((e - 1) & 1) * BH_;
      const f16* src = h0src + (size_t)pr0 * H_;
      #pragma unroll
      for (int it = 0; it < 8; ++it) {
        const int ch = tid + it * 256;     // 16B chunk, 0..2047
        const int row = ch >> 7;
        f16x8 v = *(const f16x8*)(src + ((size_t)ch << 3));
        *(f16x8*)(&ldsA[(ch << 4) ^ ((row & 7) << 4)]) = v;
      }
    }
    if (A1) {  // stage h1_P[e-2]
      const f16* h1src = (e == 1) ? hinit + BH_ : h1buf + (size_t)(e & 1) * BH_;
      const f16* src = h1src + (size_t)pr0 * H_;
      #pragma unroll
      for (int it = 0; it < 8; ++it) {
        const int ch = tid + it * 256;
        const int row = ch >> 7;
        f16x8 v = *(const f16x8*)(src + ((size_t)ch << 3));
        *(f16x8*)(&smB.b[(ch << 4) ^ ((row & 7) << 4)]) = v;
      }
    }
    __syncthreads();

    f32x4 acc0[2] = {};
    f32x4 acc1[2] = {};
    #pragma unroll
    for (int j = 0; j < 8; ++j) {
      const int k = (p * 8 + j) * 32 + lkq;
      f16x8 a = *(const f16x8*)(&ldsA[(lr * 2048 + k * 2) ^ ((lr & 7) << 4)]);
      if (A0) {
        #pragma unroll
        for (int cf = 0; cf < 2; ++cf)
          acc0[cf] = __builtin_amdgcn_mfma_f32_16x16x32_f16(a, l0w[cf][j], acc0[cf], 0, 0, 0);
      }
      if (A1) {
        #pragma unroll
        for (int cf = 0; cf < 2; ++cf)
          acc1[cf] = __builtin_amdgcn_mfma_f32_16x16x32_f16(a, l1aw[cf][j], acc1[cf], 0, 0, 0);
      }
    }
    if (A1) {
      #pragma unroll
      for (int j = 0; j < 8; ++j) {
        const int k = (p * 8 + j) * 32 + lkq;
        f16x8 a = *(const f16x8*)(&smB.b[(lr * 2048 + k * 2) ^ ((lr & 7) << 4)]);
        #pragma unroll
        for (int cf = 0; cf < 2; ++cf)
          acc1[cf] = __builtin_amdgcn_mfma_f32_16x16x32_f16(a, l1bw[cf][j], acc1[cf], 0, 0, 0);
      }
    }
    __syncthreads();   // protect smB union (staging -> exchange)

    #pragma unroll
    for (int cf = 0; cf < 2; ++cf)
      #pragma unroll
      for (int ri = 0; ri < 4; ++ri) {
        if (A0) smB.exc[0][p][lrq + ri][cf * 16 + lr] = acc0[cf][ri];
        if (A1) smB.exc[1][p][lrq + ri][cf * 16 + lr] = acc1[cf][ri];
      }
    __syncthreads();

    // cell update: pod-P threads only (128 of 256)
    if (tp == P) {
      if (A0) {
        float gv[4];
        #pragma unroll
        for (int g = 0; g < 4; ++g)
          gv[g] = smB.exc[0][0][crow][g * 8 + cu] + smB.exc[0][1][crow][g * 8 + cu]
                + smB.exc[0][2][crow][g * 8 + cu] + smB.exc[0][3][crow][g * 8 + cu] + pf[g];
        const float cn = sigf(gv[1]) * c0 + sigf(gv[0]) * tanhf_fast(gv[2]);
        const float hn = sigf(gv[3]) * tanhf_fast(cn);
        c0 = cn;
        smH[0][crow][cu] = (f16)hn;
        if (e == T_ - 1) { st_f32g(&outh[cell], hn); st_f32g(&outc[cell], cn); }
      }
      if (A1) {
        const int t = e - 1;
        float gv[4];
        #pragma unroll
        for (int g = 0; g < 4; ++g)
          gv[g] = smB.exc[1][0][crow][g * 8 + cu] + smB.exc[1][1][crow][g * 8 + cu]
                + smB.exc[1][2][crow][g * 8 + cu] + smB.exc[1][3][crow][g * 8 + cu] + b1v[g];
        const float cn = sigf(gv[1]) * c1 + sigf(gv[0]) * tanhf_fast(gv[2]);
        const float hn = sigf(gv[3]) * tanhf_fast(cn);
        c1 = cn;
        smH[1][crow][cu] = (f16)hn;
        st_f32g(&out[(size_t)prow * (T_ * H_) + (size_t)t * H_ + ub + cu], hn);
        if (e == T_) { st_f32g(&outh[BH_ + cell], hn); st_f32g(&outc[BH_ + cell], cn); }
      }
    }
    __syncthreads();

    // publish h slices (wave 0): lanes 0-31 -> h0, lanes 32-63 -> h1
    if (p == 0) {
      if (A0 && lane < 32) {
        const int row = lane >> 1, half = lane & 1;
        unsigned long long v = *(const unsigned long long*)&smH[0][row][half * 4];
        st_u64g((unsigned long long*)(h0buf + (size_t)(e & 1) * BH_
                                      + (size_t)(pr0 + row) * H_ + ub + half * 4), v);
      }
      if (A1 && lane >= 32) {
        const int l = lane - 32;
        const int row = l >> 1, half = l & 1;
        unsigned long long v = *(const unsigned long long*)&smH[1][row][half * 4];
        st_u64g((unsigned long long*)(h1buf + (size_t)((e - 1) & 1) * BH_
                                      + (size_t)(pr0 + row) * H_ + ub + half * 4), v);
      }
      asm volatile("s_waitcnt vmcnt(0)" ::: "memory");
      if (tid == 0) st_u32g(&flags[P * 256 + wg], (unsigned)(e + 1));
    }
  };

  // epoch loop: phases A(e), B(e)
  phase(BC<true>{}, BC<false>{}, 0, 0);
  phase(BC<true>{}, BC<false>{}, 1, 0);
  for (int e = 1; e < T_; ++e) {
    phase(BC<true>{}, BC<true>{}, 0, e);
    phase(BC<true>{}, BC<true>{}, 1, e);
  }
  phase(BC<false>{}, BC<true>{}, 0, T_);
  phase(BC<false>{}, BC<true>{}, 1, T_);
}

// ---------------------------------------------------------------------------
extern "C" void kernel_launch(void* const* d_in, const int* in_sizes, int n_in,
                              void* d_out, int out_size, void* d_ws, size_t ws_size,
                              hipStream_t stream)
{
  const float* x    = (const float*)d_in[0];
  const float* h    = (const float*)d_in[1];
  const float* c    = (const float*)d_in[2];
  const float* Wih0 = (const float*)d_in[3];
  const float* Whh0 = (const float*)d_in[4];
  const float* bih0 = (const float*)d_in[5];
  const float* bhh0 = (const float*)d_in[6];
  const float* Wih1 = (const float*)d_in[7];
  const float* Whh1 = (const float*)d_in[8];
  const float* bih1 = (const float*)d_in[9];
  const float* bhh1 = (const float*)d_in[10];

  char* w = (char*)d_ws;
  size_t off = 0;
  auto carve = [&](size_t bytes) -> char* {
    char* ptr = w + off;
    off = (off + bytes + 255) & ~(size_t)255;
    return ptr;
  };
  f16*   pre0T = (f16*)  carve((size_t)T_ * B_ * FH_ * 2);
  f16*   xT    = (f16*)  carve((size_t)T_ * B_ * N_ * 2);
  f16*   wih0  = (f16*)  carve((size_t)FH_ * N_ * 2);
  f16*   whh0  = (f16*)  carve((size_t)FH_ * H_ * 2);
  f16*   wih1  = (f16*)  carve((size_t)FH_ * H_ * 2);
  f16*   whh1  = (f16*)  carve((size_t)FH_ * H_ * 2);
  float* bias0 = (float*)carve((size_t)FH_ * 4);
  float* bias1 = (float*)carve((size_t)FH_ * 4);
  f16*   hinit = (f16*)  carve((size_t)2 * BH_ * 2);
  f16*   h0buf = (f16*)  carve((size_t)2 * BH_ * 2);
  f16*   h1buf = (f16*)  carve((size_t)2 * BH_ * 2);
  unsigned* flags = (unsigned*)carve(512 * 4);
  if (off > ws_size) return;

  init_all<<<2048, 256, 0, stream>>>(x, h, Wih0, bih0, bhh0, Whh0, Wih1, Whh1, bih1, bhh1,
                                     xT, wih0, whh0, wih1, whh1, bias0, bias1, hinit, flags);
  gemm_pre0<<<4096, 256, 0, stream>>>(xT, wih0, bias0, pre0T);
  lstm_seq<<<NWG_SEQ, 256, 0, stream>>>(pre0T, whh0, wih1, whh1, bias1, hinit, (const float*)c,
                                        h0buf, h1buf, (float*)d_out, flags);
}

// Round 5
// 2361.796 us; speedup vs baseline: 3.0648x; 3.0648x over previous
//
#include <hip/hip_runtime.h>
#include <hip/hip_bf16.h>

// ---------------------------------------------------------------------------
// 2-layer LSTM, B=64 T=256 N=512 H=1024.
// R5: fence-free dataflow. Consumers read h straight into MFMA fragments via
// uncached (sc0 sc1) loads -> no L2 invalidate, cached state stays hot.
// No LDS A-staging. Sync = per-(pod,epoch) arrival counter (relaxed
// atomicAdd) + single-word poll. Weights pinned in VGPRs (~370 VGPR @ 1
// wave/SIMD). Two spatial pods of 128 WGs (batch rows 0-31 / 32-63).
// ---------------------------------------------------------------------------

#define T_ 256
#define B_ 64
#define N_ 512
#define H_ 1024
#define FH_ 4096
#define NWG_SEQ 256
#define BH_ (B_ * H_)

typedef _Float16 f16;
typedef _Float16 f16x4 __attribute__((ext_vector_type(4)));
typedef _Float16 f16x8 __attribute__((ext_vector_type(8)));
typedef float f32x4 __attribute__((ext_vector_type(4)));

template <bool V> struct BC { static constexpr bool value = V; };

__device__ __forceinline__ float sigf(float x) { return 1.f / (1.f + __expf(-x)); }
__device__ __forceinline__ float tanhf_fast(float x) { return 1.f - 2.f / (__expf(2.f * x) + 1.f); }

// uncached (bypass L1/L2, MALL-coherent) accessors
__device__ __forceinline__ void st_u64g(unsigned long long* p, unsigned long long v) {
  __hip_atomic_store(p, v, __ATOMIC_RELAXED, __HIP_MEMORY_SCOPE_AGENT);
}
__device__ __forceinline__ f16x8 ld_b128_nc(const f16* p) {
  f16x8 r;
  asm volatile("global_load_dwordx4 %0, %1, off sc0 sc1" : "=v"(r) : "v"(p));
  return r;
}

// ---------------------------------------------------------------------------
// init / convert kernel
// ---------------------------------------------------------------------------
__global__ __launch_bounds__(256) void init_all(
    const float* __restrict__ x, const float* __restrict__ h,
    const float* __restrict__ Wih0, const float* __restrict__ bih0, const float* __restrict__ bhh0,
    const float* __restrict__ Whh0, const float* __restrict__ Wih1, const float* __restrict__ Whh1,
    const float* __restrict__ bih1, const float* __restrict__ bhh1,
    f16* __restrict__ xT, f16* __restrict__ wih0, f16* __restrict__ whh0,
    f16* __restrict__ wih1, f16* __restrict__ whh1,
    float* __restrict__ bias0, float* __restrict__ bias1,
    f16* __restrict__ hinit, unsigned* __restrict__ cnt)
{
  const int stride = gridDim.x * blockDim.x;
  const int t0 = blockIdx.x * blockDim.x + threadIdx.x;

  for (int i = t0; i < T_ * B_ * N_; i += stride) {
    int n = i & (N_ - 1);
    int tb = i >> 9;
    int b = tb & (B_ - 1);
    int t = tb >> 6;
    xT[i] = (f16)x[((size_t)b * T_ + t) * N_ + n];
  }
  for (int i = t0; i < FH_ * N_; i += stride) wih0[i] = (f16)Wih0[i];
  for (int i = t0; i < FH_ * H_; i += stride) {
    whh0[i] = (f16)Whh0[i];
    wih1[i] = (f16)Wih1[i];
    whh1[i] = (f16)Whh1[i];
  }
  for (int i = t0; i < FH_; i += stride) {
    bias0[i] = bih0[i] + bhh0[i];
    bias1[i] = bih1[i] + bhh1[i];
  }
  for (int i = t0; i < 2 * BH_; i += stride) hinit[i] = (f16)h[i];
  if (t0 < 1024) cnt[t0] = 0u;
}

// ---------------------------------------------------------------------------
// GEMM: pre0T[t][col][b] = (xT @ wih0^T + bias0), stored f16 TRANSPOSED.
// ---------------------------------------------------------------------------
__global__ __launch_bounds__(256) void gemm_pre0(
    const f16* __restrict__ xT, const f16* __restrict__ wih0,
    const float* __restrict__ bias0, f16* __restrict__ pre0T)
{
  const int wid = threadIdx.x >> 6;
  const int lane = threadIdx.x & 63;
  const int lr = lane & 15;
  const int lkq = (lane >> 4) << 3;
  const int lrq = (lane >> 4) << 2;

  const int mt = blockIdx.x & 255;
  const int ct = (blockIdx.x >> 8) * 4 + wid;
  const int row0 = mt * 64, col0 = ct * 64;

  f32x4 acc[4][4] = {};
  const f16* Abase = xT + (size_t)row0 * N_;

  #pragma unroll 2
  for (int kk = 0; kk < N_ / 32; ++kk) {
    const int k = kk * 32 + lkq;
    f16x8 a[4], b[4];
    #pragma unroll
    for (int r = 0; r < 4; ++r)
      a[r] = *(const f16x8*)(Abase + (size_t)(r * 16 + lr) * N_ + k);
    #pragma unroll
    for (int cf = 0; cf < 4; ++cf)
      b[cf] = *(const f16x8*)(wih0 + (size_t)(col0 + cf * 16 + lr) * N_ + k);
    #pragma unroll
    for (int r = 0; r < 4; ++r)
      #pragma unroll
      for (int cf = 0; cf < 4; ++cf)
        acc[r][cf] = __builtin_amdgcn_mfma_f32_16x16x32_f16(a[r], b[cf], acc[r][cf], 0, 0, 0);
  }

  #pragma unroll
  for (int r = 0; r < 4; ++r) {
    #pragma unroll
    for (int cf = 0; cf < 4; ++cf) {
      const int col = col0 + cf * 16 + lr;
      const float bv = bias0[col];
      f16x4 pv;
      #pragma unroll
      for (int ri = 0; ri < 4; ++ri) pv[ri] = (f16)(acc[r][cf][ri] + bv);
      *(f16x4*)(pre0T + ((size_t)mt * FH_ + col) * 64 + r * 16 + lrq) = pv;
    }
  }
}

// ---------------------------------------------------------------------------
// Persistent fence-free dataflow kernel. 256 WGs x 256 threads (1 WG/CU).
// Pod P = 128 WGs, batch rows P*32..P*32+31. WG owns 8 units of each gate.
// Per epoch e: layer0 step e + layer1 step e-1 (same as R3 pipeline).
// cnt[P*512 + e] counts pod WGs that completed phase e.
// ---------------------------------------------------------------------------
__global__ __launch_bounds__(256, 1) void lstm_seq(
    const f16* __restrict__ pre0T, const f16* __restrict__ whh0,
    const f16* __restrict__ wih1, const f16* __restrict__ whh1,
    const float* __restrict__ bias1, const f16* __restrict__ hinit,
    const float* __restrict__ cin,
    f16* __restrict__ h0buf, f16* __restrict__ h1buf,
    float* __restrict__ out, unsigned* __restrict__ cnt)
{
  __shared__ __align__(16) float exc[2][4][32][33];   // partial-sum exchange
  __shared__ __align__(16) f16 smH[2][32][8];         // packed h outputs

  const int tid = threadIdx.x;
  const int p = tid >> 6;          // wave = K-quarter
  const int lane = tid & 63;
  const int lr = lane & 15;
  const int lq = lane >> 4;
  const int lkq = lq << 3;
  const int lrq = lq << 2;

  const int wg = blockIdx.x;
  const int pod = wg >> 7;         // 0: rows 0..31, 1: rows 32..63
  const int slot = wg & 127;
  const int rs = pod << 5;
  const int ub = slot << 3;        // unit base: 8 units per gate
  unsigned* podcnt = cnt + (pod << 9);

  // ---- preload weight fragments into registers (48 x f16x8) ----
  f16x8 l0w[2][8], l1aw[2][8], l1bw[2][8];
  #pragma unroll
  for (int cf = 0; cf < 2; ++cf) {
    const size_t wr = (size_t)((2 * cf + (lr >> 3)) * H_ + ub + (lr & 7)) * H_;
    #pragma unroll
    for (int j = 0; j < 8; ++j) {
      const int k = (p * 8 + j) * 32 + lkq;
      l0w[cf][j]  = *(const f16x8*)(whh0 + wr + k);
      l1aw[cf][j] = *(const f16x8*)(wih1 + wr + k);
      l1bw[cf][j] = *(const f16x8*)(whh1 + wr + k);
    }
  }

  // ---- per-thread cell state ----
  const int crow = tid & 31;
  const int cu = tid >> 5;
  const size_t cell = (size_t)(rs + crow) * H_ + ub + cu;
  float c0 = cin[cell];
  float c1 = cin[(size_t)BH_ + cell];
  float b1v[4];
  #pragma unroll
  for (int g = 0; g < 4; ++g) b1v[g] = bias1[g * H_ + ub + cu];

  float* outh = out + (size_t)B_ * T_ * H_;
  float* outc = outh + 2 * BH_;

  auto body = [&](auto A0c, auto A1c, int e) {
    constexpr bool A0 = decltype(A0c)::value;
    constexpr bool A1 = decltype(A1c)::value;

    // pre0 additive term: cached loads (L2 stays hot -- no fences anywhere)
    float pf[4];
    if (A0) {
      #pragma unroll
      for (int g = 0; g < 4; ++g)
        pf[g] = (float)pre0T[((size_t)e * FH_ + g * H_ + ub + cu) * 64 + rs + crow];
    }

    // poll: all 128 pod WGs completed phase e-1 (single word, single lane)
    if (e > 0) {
      if (tid == 0) {
        while (__hip_atomic_load(&podcnt[e - 1], __ATOMIC_RELAXED, __HIP_MEMORY_SCOPE_AGENT) < 128u)
          __builtin_amdgcn_s_sleep(2);
      }
      __syncthreads();
    }

    // ---- fragment loads, uncached, straight from h rings at MALL ----
    const f16* h0s = ((e == 0) ? hinit : h0buf + (size_t)((e - 1) & 1) * BH_) + (size_t)rs * H_;
    const f16* h1s = A1 ? (((e == 1) ? hinit + BH_ : h1buf + (size_t)(e & 1) * BH_) + (size_t)rs * H_)
                        : (const f16*)nullptr;
    f16x8 a0v[8], a1v[8], c0v[8], c1v[8];
    #pragma unroll
    for (int j = 0; j < 8; ++j) {
      const int k = (p * 8 + j) * 32 + lkq;
      a0v[j] = ld_b128_nc(h0s + (size_t)lr * H_ + k);
      a1v[j] = ld_b128_nc(h0s + (size_t)(16 + lr) * H_ + k);
    }
    if (A1) {
      #pragma unroll
      for (int j = 0; j < 8; ++j) {
        const int k = (p * 8 + j) * 32 + lkq;
        c0v[j] = ld_b128_nc(h1s + (size_t)lr * H_ + k);
        c1v[j] = ld_b128_nc(h1s + (size_t)(16 + lr) * H_ + k);
      }
    }
    asm volatile("s_waitcnt vmcnt(0)" ::: "memory");
    __builtin_amdgcn_sched_barrier(0);

    // ---- MFMAs: layer0 (whh0) + layer1 (wih1 on h0, whh1 on h1) ----
    f32x4 acc0[2][2] = {};
    f32x4 acc1[2][2] = {};
    #pragma unroll
    for (int j = 0; j < 8; ++j) {
      if (A0) {
        #pragma unroll
        for (int cf = 0; cf < 2; ++cf) {
          acc0[cf][0] = __builtin_amdgcn_mfma_f32_16x16x32_f16(a0v[j], l0w[cf][j], acc0[cf][0], 0, 0, 0);
          acc0[cf][1] = __builtin_amdgcn_mfma_f32_16x16x32_f16(a1v[j], l0w[cf][j], acc0[cf][1], 0, 0, 0);
        }
      }
      if (A1) {
        #pragma unroll
        for (int cf = 0; cf < 2; ++cf) {
          acc1[cf][0] = __builtin_amdgcn_mfma_f32_16x16x32_f16(a0v[j], l1aw[cf][j], acc1[cf][0], 0, 0, 0);
          acc1[cf][1] = __builtin_amdgcn_mfma_f32_16x16x32_f16(a1v[j], l1aw[cf][j], acc1[cf][1], 0, 0, 0);
        }
      }
    }
    if (A1) {
      #pragma unroll
      for (int j = 0; j < 8; ++j) {
        #pragma unroll
        for (int cf = 0; cf < 2; ++cf) {
          acc1[cf][0] = __builtin_amdgcn_mfma_f32_16x16x32_f16(c0v[j], l1bw[cf][j], acc1[cf][0], 0, 0, 0);
          acc1[cf][1] = __builtin_amdgcn_mfma_f32_16x16x32_f16(c1v[j], l1bw[cf][j], acc1[cf][1], 0, 0, 0);
        }
      }
    }

    // ---- partial-sum exchange (exc last read pre-publish last epoch) ----
    #pragma unroll
    for (int cf = 0; cf < 2; ++cf)
      #pragma unroll
      for (int rf = 0; rf < 2; ++rf)
        #pragma unroll
        for (int ri = 0; ri < 4; ++ri) {
          if (A0) exc[0][p][rf * 16 + lrq + ri][cf * 16 + lr] = acc0[cf][rf][ri];
          if (A1) exc[1][p][rf * 16 + lrq + ri][cf * 16 + lr] = acc1[cf][rf][ri];
        }
    __syncthreads();

    // ---- cell update (out/final stores cached: no in-kernel reader) ----
    if (A0) {
      float gv[4];
      #pragma unroll
      for (int g = 0; g < 4; ++g)
        gv[g] = exc[0][0][crow][g * 8 + cu] + exc[0][1][crow][g * 8 + cu]
              + exc[0][2][crow][g * 8 + cu] + exc[0][3][crow][g * 8 + cu] + pf[g];
      const float cn = sigf(gv[1]) * c0 + sigf(gv[0]) * tanhf_fast(gv[2]);
      const float hn = sigf(gv[3]) * tanhf_fast(cn);
      c0 = cn;
      smH[0][crow][cu] = (f16)hn;
      if (e == T_ - 1) { outh[cell] = hn; outc[cell] = cn; }
    }
    if (A1) {
      const int t = e - 1;
      float gv[4];
      #pragma unroll
      for (int g = 0; g < 4; ++g)
        gv[g] = exc[1][0][crow][g * 8 + cu] + exc[1][1][crow][g * 8 + cu]
              + exc[1][2][crow][g * 8 + cu] + exc[1][3][crow][g * 8 + cu] + b1v[g];
      const float cn = sigf(gv[1]) * c1 + sigf(gv[0]) * tanhf_fast(gv[2]);
      const float hn = sigf(gv[3]) * tanhf_fast(cn);
      c1 = cn;
      smH[1][crow][cu] = (f16)hn;
      out[(size_t)(rs + crow) * (T_ * H_) + (size_t)t * H_ + ub + cu] = hn;
      if (e == T_) { outh[BH_ + cell] = hn; outc[BH_ + cell] = cn; }
    }
    __syncthreads();

    // ---- publish h slices uncached (wave0: h0, wave1: h1), drain, arrive --
    if (A0 && p == 0) {
      const int row = lane >> 1, half = lane & 1;
      unsigned long long v = *(const unsigned long long*)&smH[0][row][half * 4];
      st_u64g((unsigned long long*)(h0buf + (size_t)(e & 1) * BH_
                                    + (size_t)(rs + row) * H_ + ub + half * 4), v);
    }
    if (A1 && p == 1) {
      const int row = lane >> 1, half = lane & 1;
      unsigned long long v = *(const unsigned long long*)&smH[1][row][half * 4];
      st_u64g((unsigned long long*)(h1buf + (size_t)((e - 1) & 1) * BH_
                                    + (size_t)(rs + row) * H_ + ub + half * 4), v);
    }
    asm volatile("s_waitcnt vmcnt(0)" ::: "memory");
    __syncthreads();
    if (tid == 0)
      (void)__hip_atomic_fetch_add(&podcnt[e], 1u, __ATOMIC_RELAXED, __HIP_MEMORY_SCOPE_AGENT);
  };

  body(BC<true>{}, BC<false>{}, 0);
  for (int e = 1; e < T_; ++e) body(BC<true>{}, BC<true>{}, e);
  body(BC<false>{}, BC<true>{}, T_);
}

// ---------------------------------------------------------------------------
extern "C" void kernel_launch(void* const* d_in, const int* in_sizes, int n_in,
                              void* d_out, int out_size, void* d_ws, size_t ws_size,
                              hipStream_t stream)
{
  const float* x    = (const float*)d_in[0];
  const float* h    = (const float*)d_in[1];
  const float* c    = (const float*)d_in[2];
  const float* Wih0 = (const float*)d_in[3];
  const float* Whh0 = (const float*)d_in[4];
  const float* bih0 = (const float*)d_in[5];
  const float* bhh0 = (const float*)d_in[6];
  const float* Wih1 = (const float*)d_in[7];
  const float* Whh1 = (const float*)d_in[8];
  const float* bih1 = (const float*)d_in[9];
  const float* bhh1 = (const float*)d_in[10];

  char* w = (char*)d_ws;
  size_t off = 0;
  auto carve = [&](size_t bytes) -> char* {
    char* ptr = w + off;
    off = (off + bytes + 255) & ~(size_t)255;
    return ptr;
  };
  f16*   pre0T = (f16*)  carve((size_t)T_ * B_ * FH_ * 2);
  f16*   xT    = (f16*)  carve((size_t)T_ * B_ * N_ * 2);
  f16*   wih0  = (f16*)  carve((size_t)FH_ * N_ * 2);
  f16*   whh0  = (f16*)  carve((size_t)FH_ * H_ * 2);
  f16*   wih1  = (f16*)  carve((size_t)FH_ * H_ * 2);
  f16*   whh1  = (f16*)  carve((size_t)FH_ * H_ * 2);
  float* bias0 = (float*)carve((size_t)FH_ * 4);
  float* bias1 = (float*)carve((size_t)FH_ * 4);
  f16*   hinit = (f16*)  carve((size_t)2 * BH_ * 2);
  f16*   h0buf = (f16*)  carve((size_t)2 * BH_ * 2);
  f16*   h1buf = (f16*)  carve((size_t)2 * BH_ * 2);
  unsigned* cnt = (unsigned*)carve(1024 * 4);
  if (off > ws_size) return;

  init_all<<<2048, 256, 0, stream>>>(x, h, Wih0, bih0, bhh0, Whh0, Wih1, Whh1, bih1, bhh1,
                                     xT, wih0, whh0, wih1, whh1, bias0, bias1, hinit, cnt);
  gemm_pre0<<<4096, 256, 0, stream>>>(xT, wih0, bias0, pre0T);
  lstm_seq<<<NWG_SEQ, 256, 0, stream>>>(pre0T, whh0, wih1, whh1, bias1, hinit, (const float*)c,
                                        h0buf, h1buf, (float*)d_out, cnt);
}

// Round 6
// 1934.426 us; speedup vs baseline: 3.7419x; 1.2209x over previous
//
#include <hip/hip_runtime.h>
#include <hip/hip_bf16.h>

// ---------------------------------------------------------------------------
// 2-layer LSTM, B=64 T=256 N=512 H=1024.
// R6: write-once h rings (T-deep, unique addresses) -> consumers use PLAIN
// CACHED loads (L2 broadcasts within each XCD, no staleness possible, no
// fences). Producers publish uncached (MALL write-through) + per-(pod,layer,
// epoch) arrival counters. Layer-0 publishes before layer-1 work (shorter
// serial chain). Weights pinned in VGPRs/AGPRs. Fallback template if ws too
// small keeps the R5 uncached-load path.
// ---------------------------------------------------------------------------

#define T_ 256
#define B_ 64
#define N_ 512
#define H_ 1024
#define FH_ 4096
#define NWG_SEQ 256
#define BH_ (B_ * H_)

typedef _Float16 f16;
typedef _Float16 f16x4 __attribute__((ext_vector_type(4)));
typedef _Float16 f16x8 __attribute__((ext_vector_type(8)));
typedef float f32x4 __attribute__((ext_vector_type(4)));

template <bool V> struct BC { static constexpr bool value = V; };

__device__ __forceinline__ float sigf(float x) { return 1.f / (1.f + __expf(-x)); }
__device__ __forceinline__ float tanhf_fast(float x) { return 1.f - 2.f / (__expf(2.f * x) + 1.f); }

// uncached (bypass L1/L2, MALL-coherent) accessors
__device__ __forceinline__ void st_u64g(unsigned long long* p, unsigned long long v) {
  __hip_atomic_store(p, v, __ATOMIC_RELAXED, __HIP_MEMORY_SCOPE_AGENT);
}
__device__ __forceinline__ f16x8 ld_b128_nc(const f16* p) {
  f16x8 r;
  asm volatile("global_load_dwordx4 %0, %1, off sc0 sc1" : "=v"(r) : "v"(p));
  return r;
}

// ---------------------------------------------------------------------------
// init / convert kernel
// ---------------------------------------------------------------------------
__global__ __launch_bounds__(256) void init_all(
    const float* __restrict__ x, const float* __restrict__ h,
    const float* __restrict__ Wih0, const float* __restrict__ bih0, const float* __restrict__ bhh0,
    const float* __restrict__ Whh0, const float* __restrict__ Wih1, const float* __restrict__ Whh1,
    const float* __restrict__ bih1, const float* __restrict__ bhh1,
    f16* __restrict__ xT, f16* __restrict__ wih0, f16* __restrict__ whh0,
    f16* __restrict__ wih1, f16* __restrict__ whh1,
    float* __restrict__ bias0, float* __restrict__ bias1,
    f16* __restrict__ hinit, unsigned* __restrict__ cnt)
{
  const int stride = gridDim.x * blockDim.x;
  const int t0 = blockIdx.x * blockDim.x + threadIdx.x;

  for (int i = t0; i < T_ * B_ * N_; i += stride) {
    int n = i & (N_ - 1);
    int tb = i >> 9;
    int b = tb & (B_ - 1);
    int t = tb >> 6;
    xT[i] = (f16)x[((size_t)b * T_ + t) * N_ + n];
  }
  for (int i = t0; i < FH_ * N_; i += stride) wih0[i] = (f16)Wih0[i];
  for (int i = t0; i < FH_ * H_; i += stride) {
    whh0[i] = (f16)Whh0[i];
    wih1[i] = (f16)Wih1[i];
    whh1[i] = (f16)Whh1[i];
  }
  for (int i = t0; i < FH_; i += stride) {
    bias0[i] = bih0[i] + bhh0[i];
    bias1[i] = bih1[i] + bhh1[i];
  }
  for (int i = t0; i < 2 * BH_; i += stride) hinit[i] = (f16)h[i];
  if (t0 < 2048) cnt[t0] = 0u;
}

// ---------------------------------------------------------------------------
// GEMM: pre0T[t][col][b] = (xT @ wih0^T + bias0), stored f16 TRANSPOSED.
// ---------------------------------------------------------------------------
__global__ __launch_bounds__(256) void gemm_pre0(
    const f16* __restrict__ xT, const f16* __restrict__ wih0,
    const float* __restrict__ bias0, f16* __restrict__ pre0T)
{
  const int wid = threadIdx.x >> 6;
  const int lane = threadIdx.x & 63;
  const int lr = lane & 15;
  const int lkq = (lane >> 4) << 3;
  const int lrq = (lane >> 4) << 2;

  const int mt = blockIdx.x & 255;
  const int ct = (blockIdx.x >> 8) * 4 + wid;
  const int row0 = mt * 64, col0 = ct * 64;

  f32x4 acc[4][4] = {};
  const f16* Abase = xT + (size_t)row0 * N_;

  #pragma unroll 2
  for (int kk = 0; kk < N_ / 32; ++kk) {
    const int k = kk * 32 + lkq;
    f16x8 a[4], b[4];
    #pragma unroll
    for (int r = 0; r < 4; ++r)
      a[r] = *(const f16x8*)(Abase + (size_t)(r * 16 + lr) * N_ + k);
    #pragma unroll
    for (int cf = 0; cf < 4; ++cf)
      b[cf] = *(const f16x8*)(wih0 + (size_t)(col0 + cf * 16 + lr) * N_ + k);
    #pragma unroll
    for (int r = 0; r < 4; ++r)
      #pragma unroll
      for (int cf = 0; cf < 4; ++cf)
        acc[r][cf] = __builtin_amdgcn_mfma_f32_16x16x32_f16(a[r], b[cf], acc[r][cf], 0, 0, 0);
  }

  #pragma unroll
  for (int r = 0; r < 4; ++r) {
    #pragma unroll
    for (int cf = 0; cf < 4; ++cf) {
      const int col = col0 + cf * 16 + lr;
      const float bv = bias0[col];
      f16x4 pv;
      #pragma unroll
      for (int ri = 0; ri < 4; ++ri) pv[ri] = (f16)(acc[r][cf][ri] + bv);
      *(f16x4*)(pre0T + ((size_t)mt * FH_ + col) * 64 + r * 16 + lrq) = pv;
    }
  }
}

// ---------------------------------------------------------------------------
// Persistent dataflow kernel. 256 WGs x 256 threads (1 WG/CU).
// Pod P = 128 WGs, batch rows P*32..P*32+31. WG owns 8 units of each gate.
// Epoch e: layer0 step e (publish first), layer1 step e-1.
// cnt layout: [pod*2 + layer][epoch].
// ---------------------------------------------------------------------------
template <bool DEEP>
__global__ __launch_bounds__(256, 1) void lstm_seq(
    const f16* __restrict__ pre0T, const f16* __restrict__ whh0,
    const f16* __restrict__ wih1, const f16* __restrict__ whh1,
    const float* __restrict__ bias1, const f16* __restrict__ hinit,
    const float* __restrict__ cin,
    f16* __restrict__ h0ring, f16* __restrict__ h1ring,
    f16* __restrict__ h0buf, f16* __restrict__ h1buf,
    float* __restrict__ out, unsigned* __restrict__ cnt)
{
  __shared__ __align__(16) float exc[2][4][32][33];   // partial-sum exchange
  __shared__ __align__(16) f16 smH[2][32][8];         // packed h outputs

  const int tid = threadIdx.x;
  const int p = tid >> 6;          // wave = K-quarter
  const int lane = tid & 63;
  const int lr = lane & 15;
  const int lq = lane >> 4;
  const int lkq = lq << 3;
  const int lrq = lq << 2;

  const int wg = blockIdx.x;
  const int pod = wg >> 7;         // 0: rows 0..31, 1: rows 32..63
  const int slot = wg & 127;
  const int rs = pod << 5;
  const int ub = slot << 3;        // unit base: 8 units per gate
  unsigned* podc0 = cnt + (size_t)(pod * 2) * 512;
  unsigned* podc1 = cnt + (size_t)(pod * 2 + 1) * 512;

  // ---- preload weight fragments into registers (48 x f16x8) ----
  f16x8 l0w[2][8], l1aw[2][8], l1bw[2][8];
  #pragma unroll
  for (int cf = 0; cf < 2; ++cf) {
    const size_t wr = (size_t)((2 * cf + (lr >> 3)) * H_ + ub + (lr & 7)) * H_;
    #pragma unroll
    for (int j = 0; j < 8; ++j) {
      const int k = (p * 8 + j) * 32 + lkq;
      l0w[cf][j]  = *(const f16x8*)(whh0 + wr + k);
      l1aw[cf][j] = *(const f16x8*)(wih1 + wr + k);
      l1bw[cf][j] = *(const f16x8*)(whh1 + wr + k);
    }
  }

  // ---- per-thread cell state ----
  const int crow = tid & 31;
  const int cu = tid >> 5;
  const size_t cell = (size_t)(rs + crow) * H_ + ub + cu;
  float c0 = cin[cell];
  float c1 = cin[(size_t)BH_ + cell];
  float b1v[4];
  #pragma unroll
  for (int g = 0; g < 4; ++g) b1v[g] = bias1[g * H_ + ub + cu];

  float* outh = out + (size_t)B_ * T_ * H_;
  float* outc = outh + 2 * BH_;

  auto poll = [&](unsigned* word) {
    if (tid == 0) {
      while (__hip_atomic_load(word, __ATOMIC_RELAXED, __HIP_MEMORY_SCOPE_AGENT) < 128u)
        __builtin_amdgcn_s_sleep(1);
    }
    __syncthreads();
  };

  auto body = [&](auto A0c, auto A1c, int e) {
    constexpr bool A0 = decltype(A0c)::value;
    constexpr bool A1 = decltype(A1c)::value;

    // pre0 additive term: cached, ungated
    float pf[4];
    if (A0) {
      #pragma unroll
      for (int g = 0; g < 4; ++g)
        pf[g] = (float)pre0T[((size_t)e * FH_ + g * H_ + ub + cu) * 64 + rs + crow];
    }

    // ===================== phase 1: gate on h0[e-1] ========================
    if (e > 0) poll(&podc0[e - 1]);

    const f16* h0s = ((e == 0) ? hinit
                      : (DEEP ? h0ring + (size_t)(e - 1) * BH_
                              : h0buf + (size_t)((e - 1) & 1) * BH_)) + (size_t)rs * H_;
    f16x8 a0v[8], a1v[8];
    #pragma unroll
    for (int j = 0; j < 8; ++j) {
      const int k = (p * 8 + j) * 32 + lkq;
      if (DEEP) {
        a0v[j] = *(const f16x8*)(h0s + (size_t)lr * H_ + k);
        a1v[j] = *(const f16x8*)(h0s + (size_t)(16 + lr) * H_ + k);
      } else {
        a0v[j] = ld_b128_nc(h0s + (size_t)lr * H_ + k);
        a1v[j] = ld_b128_nc(h0s + (size_t)(16 + lr) * H_ + k);
      }
    }
    if (!DEEP) {
      asm volatile("s_waitcnt vmcnt(0)" ::: "memory");
      __builtin_amdgcn_sched_barrier(0);
    }

    f32x4 acc0[2][2] = {};
    f32x4 acc1[2][2] = {};
    #pragma unroll
    for (int j = 0; j < 8; ++j) {
      if (A0) {
        #pragma unroll
        for (int cf = 0; cf < 2; ++cf) {
          acc0[cf][0] = __builtin_amdgcn_mfma_f32_16x16x32_f16(a0v[j], l0w[cf][j], acc0[cf][0], 0, 0, 0);
          acc0[cf][1] = __builtin_amdgcn_mfma_f32_16x16x32_f16(a1v[j], l0w[cf][j], acc0[cf][1], 0, 0, 0);
        }
      }
      if (A1) {
        #pragma unroll
        for (int cf = 0; cf < 2; ++cf) {
          acc1[cf][0] = __builtin_amdgcn_mfma_f32_16x16x32_f16(a0v[j], l1aw[cf][j], acc1[cf][0], 0, 0, 0);
          acc1[cf][1] = __builtin_amdgcn_mfma_f32_16x16x32_f16(a1v[j], l1aw[cf][j], acc1[cf][1], 0, 0, 0);
        }
      }
    }

    // ---- layer0: exchange, update, publish EARLY ----
    if (A0) {
      #pragma unroll
      for (int cf = 0; cf < 2; ++cf)
        #pragma unroll
        for (int rf = 0; rf < 2; ++rf)
          #pragma unroll
          for (int ri = 0; ri < 4; ++ri)
            exc[0][p][rf * 16 + lrq + ri][cf * 16 + lr] = acc0[cf][rf][ri];
      __syncthreads();

      float gv[4];
      #pragma unroll
      for (int g = 0; g < 4; ++g)
        gv[g] = exc[0][0][crow][g * 8 + cu] + exc[0][1][crow][g * 8 + cu]
              + exc[0][2][crow][g * 8 + cu] + exc[0][3][crow][g * 8 + cu] + pf[g];
      const float cn = sigf(gv[1]) * c0 + sigf(gv[0]) * tanhf_fast(gv[2]);
      const float hn = sigf(gv[3]) * tanhf_fast(cn);
      c0 = cn;
      smH[0][crow][cu] = (f16)hn;
      if (e == T_ - 1) { outh[cell] = hn; outc[cell] = cn; }
      __syncthreads();

      if (p == 0) {
        const int row = lane >> 1, half = lane & 1;
        unsigned long long v = *(const unsigned long long*)&smH[0][row][half * 4];
        f16* dst = DEEP ? h0ring + (size_t)e * BH_ : h0buf + (size_t)(e & 1) * BH_;
        st_u64g((unsigned long long*)(dst + (size_t)(rs + row) * H_ + ub + half * 4), v);
      }
      asm volatile("s_waitcnt vmcnt(0)" ::: "memory");
      if (tid == 0)
        (void)__hip_atomic_fetch_add(&podc0[e], 1u, __ATOMIC_RELAXED, __HIP_MEMORY_SCOPE_AGENT);
    }

    // ===================== phase 2: gate on h1[e-2] ========================
    if (A1) {
      if (e >= 2) poll(&podc1[e - 1]);

      const f16* h1s = ((e == 1) ? hinit + BH_
                        : (DEEP ? h1ring + (size_t)(e - 2) * BH_
                                : h1buf + (size_t)(e & 1) * BH_)) + (size_t)rs * H_;
      f16x8 c0v[8], c1v[8];
      #pragma unroll
      for (int j = 0; j < 8; ++j) {
        const int k = (p * 8 + j) * 32 + lkq;
        if (DEEP) {
          c0v[j] = *(const f16x8*)(h1s + (size_t)lr * H_ + k);
          c1v[j] = *(const f16x8*)(h1s + (size_t)(16 + lr) * H_ + k);
        } else {
          c0v[j] = ld_b128_nc(h1s + (size_t)lr * H_ + k);
          c1v[j] = ld_b128_nc(h1s + (size_t)(16 + lr) * H_ + k);
        }
      }
      if (!DEEP) {
        asm volatile("s_waitcnt vmcnt(0)" ::: "memory");
        __builtin_amdgcn_sched_barrier(0);
      }

      #pragma unroll
      for (int j = 0; j < 8; ++j) {
        #pragma unroll
        for (int cf = 0; cf < 2; ++cf) {
          acc1[cf][0] = __builtin_amdgcn_mfma_f32_16x16x32_f16(c0v[j], l1bw[cf][j], acc1[cf][0], 0, 0, 0);
          acc1[cf][1] = __builtin_amdgcn_mfma_f32_16x16x32_f16(c1v[j], l1bw[cf][j], acc1[cf][1], 0, 0, 0);
        }
      }

      #pragma unroll
      for (int cf = 0; cf < 2; ++cf)
        #pragma unroll
        for (int rf = 0; rf < 2; ++rf)
          #pragma unroll
          for (int ri = 0; ri < 4; ++ri)
            exc[1][p][rf * 16 + lrq + ri][cf * 16 + lr] = acc1[cf][rf][ri];
      __syncthreads();

      const int t = e - 1;
      float gv[4];
      #pragma unroll
      for (int g = 0; g < 4; ++g)
        gv[g] = exc[1][0][crow][g * 8 + cu] + exc[1][1][crow][g * 8 + cu]
              + exc[1][2][crow][g * 8 + cu] + exc[1][3][crow][g * 8 + cu] + b1v[g];
      const float cn = sigf(gv[1]) * c1 + sigf(gv[0]) * tanhf_fast(gv[2]);
      const float hn = sigf(gv[3]) * tanhf_fast(cn);
      c1 = cn;
      smH[1][crow][cu] = (f16)hn;
      out[(size_t)(rs + crow) * (T_ * H_) + (size_t)t * H_ + ub + cu] = hn;
      if (e == T_) { outh[BH_ + cell] = hn; outc[BH_ + cell] = cn; }
      __syncthreads();

      if (p == 1) {
        const int row = lane >> 1, half = lane & 1;
        unsigned long long v = *(const unsigned long long*)&smH[1][row][half * 4];
        f16* dst = DEEP ? h1ring + (size_t)(e - 1) * BH_ : h1buf + (size_t)((e - 1) & 1) * BH_;
        st_u64g((unsigned long long*)(dst + (size_t)(rs + row) * H_ + ub + half * 4), v);
      }
      asm volatile("s_waitcnt vmcnt(0)" ::: "memory");
      if (tid == 64)
        (void)__hip_atomic_fetch_add(&podc1[e], 1u, __ATOMIC_RELAXED, __HIP_MEMORY_SCOPE_AGENT);
    }
  };

  body(BC<true>{}, BC<false>{}, 0);
  for (int e = 1; e < T_; ++e) body(BC<true>{}, BC<true>{}, e);
  body(BC<false>{}, BC<true>{}, T_);
}

// ---------------------------------------------------------------------------
extern "C" void kernel_launch(void* const* d_in, const int* in_sizes, int n_in,
                              void* d_out, int out_size, void* d_ws, size_t ws_size,
                              hipStream_t stream)
{
  const float* x    = (const float*)d_in[0];
  const float* h    = (const float*)d_in[1];
  const float* c    = (const float*)d_in[2];
  const float* Wih0 = (const float*)d_in[3];
  const float* Whh0 = (const float*)d_in[4];
  const float* bih0 = (const float*)d_in[5];
  const float* bhh0 = (const float*)d_in[6];
  const float* Wih1 = (const float*)d_in[7];
  const float* Whh1 = (const float*)d_in[8];
  const float* bih1 = (const float*)d_in[9];
  const float* bhh1 = (const float*)d_in[10];

  char* w = (char*)d_ws;
  size_t off = 0;
  auto carve = [&](size_t bytes) -> char* {
    char* ptr = w + off;
    off = (off + bytes + 255) & ~(size_t)255;
    return ptr;
  };
  f16*   pre0T = (f16*)  carve((size_t)T_ * B_ * FH_ * 2);
  f16*   xT    = (f16*)  carve((size_t)T_ * B_ * N_ * 2);
  f16*   wih0  = (f16*)  carve((size_t)FH_ * N_ * 2);
  f16*   whh0  = (f16*)  carve((size_t)FH_ * H_ * 2);
  f16*   wih1  = (f16*)  carve((size_t)FH_ * H_ * 2);
  f16*   whh1  = (f16*)  carve((size_t)FH_ * H_ * 2);
  float* bias0 = (float*)carve((size_t)FH_ * 4);
  float* bias1 = (float*)carve((size_t)FH_ * 4);
  f16*   hinit = (f16*)  carve((size_t)2 * BH_ * 2);
  f16*   h0buf = (f16*)  carve((size_t)2 * BH_ * 2);
  f16*   h1buf = (f16*)  carve((size_t)2 * BH_ * 2);
  unsigned* cnt = (unsigned*)carve(2048 * 4);
  const size_t base_end = off;
  f16*   h0ring = (f16*) carve((size_t)T_ * BH_ * 2);
  f16*   h1ring = (f16*) carve((size_t)T_ * BH_ * 2);
  const bool deep = (off <= ws_size);
  if (base_end > ws_size) return;

  init_all<<<2048, 256, 0, stream>>>(x, h, Wih0, bih0, bhh0, Whh0, Wih1, Whh1, bih1, bhh1,
                                     xT, wih0, whh0, wih1, whh1, bias0, bias1, hinit, cnt);
  gemm_pre0<<<4096, 256, 0, stream>>>(xT, wih0, bias0, pre0T);
  if (deep)
    lstm_seq<true><<<NWG_SEQ, 256, 0, stream>>>(pre0T, whh0, wih1, whh1, bias1, hinit,
                                                (const float*)c, h0ring, h1ring, h0buf, h1buf,
                                                (float*)d_out, cnt);
  else
    lstm_seq<false><<<NWG_SEQ, 256, 0, stream>>>(pre0T, whh0, wih1, whh1, bias1, hinit,
                                                 (const float*)c, h0ring, h1ring, h0buf, h1buf,
                                                 (float*)d_out, cnt);
}